// Round 1
// baseline (2305.818 us; speedup 1.0000x reference)
//
#include <hip/hip_runtime.h>

#define DEPTH 16
#define MT 32     // nodes per block
#define KC 16     // K chunk staged in LDS

__device__ __forceinline__ float sigf(float x) { return 1.0f / (1.0f + expf(-x)); }

// Computes, for one tree level, h_new/c_new for n_l nodes.
// Effective gates: column j of gate G lives at original weight row G*256 + j (j < 128).
// K layout: k in [0,128) -> x (embedding), k in [128,384) -> h0 = concat(h[2m], h[2m+1]).
__global__ __launch_bounds__(256) void tree_lstm_level(
    const int* __restrict__ node_types,
    const float* __restrict__ node_args,
    const float* __restrict__ emb,      // 128 x 128
    const float* __restrict__ Wih,      // 1024 x 128
    const float* __restrict__ Whh,      // 1024 x 256
    const float* __restrict__ bih,      // 1024
    const float* __restrict__ bhh,      // 1024
    const float* __restrict__ h_in,     // 2*n_l x 128 (unused when has_h==0)
    const float* __restrict__ c_in,
    float* __restrict__ h_out,          // n_l x 128
    float* __restrict__ c_out,
    int start, int n_l, int has_h)
{
    __shared__ __align__(16) float Ws[KC * 512];   // [lk][j][gate]
    __shared__ __align__(16) float Xs[KC][36];     // [lk][m], padded stride

    const int tid = threadIdx.x;
    const int m0 = blockIdx.x * MT;
    const int K = has_h ? 384 : 128;
    const int nchunks = K / KC;

    float acc[8][2][4];
    #pragma unroll
    for (int mm = 0; mm < 8; ++mm)
        #pragma unroll
        for (int jj = 0; jj < 2; ++jj)
            #pragma unroll
            for (int g = 0; g < 4; ++g) acc[mm][jj][g] = 0.0f;

    const int tj = tid & 63;
    const int tm = tid >> 6;

    for (int ch = 0; ch < nchunks; ++ch) {
        const int kbase = ch * KC;
        __syncthreads();
        // ---- stage W chunk: 512 eff rows x KC k -> LDS [lk][j][gate]
        #pragma unroll
        for (int it = 0; it < 8; ++it) {
            int gid = tid + 256 * it;        // 0..2047 = 512 rows * 4 kq
            int re = gid >> 2;
            int kq = gid & 3;
            int j = re & 127;
            int g = re >> 7;
            int row = g * 256 + j;
            int k = kbase + kq * 4;
            float4 w;
            if (k < 128) w = *(const float4*)(Wih + row * 128 + k);
            else         w = *(const float4*)(Whh + row * 256 + (k - 128));
            int lk = kq * 4;
            Ws[(lk + 0) * 512 + j * 4 + g] = w.x;
            Ws[(lk + 1) * 512 + j * 4 + g] = w.y;
            Ws[(lk + 2) * 512 + j * 4 + g] = w.z;
            Ws[(lk + 3) * 512 + j * 4 + g] = w.w;
        }
        // ---- stage X chunk: 32 nodes x KC k
        if (tid < 128) {
            int m = tid >> 2;
            int kq = tid & 3;
            int k = kbase + kq * 4;
            int mG = m0 + m;
            float4 x = make_float4(0.f, 0.f, 0.f, 0.f);
            if (mG < n_l) {
                if (k < 128) {
                    int ty = node_types[start + mG];
                    x = *(const float4*)(emb + ty * 128 + k);
                    if (k == 124 && (ty == 1 || ty == 2)) x.w = node_args[start + mG];
                } else {
                    int kk = k - 128;
                    int row = 2 * mG + (kk >> 7);
                    int col = kk & 127;
                    x = *(const float4*)(h_in + row * 128 + col);
                }
            }
            int lk = kq * 4;
            Xs[lk + 0][m] = x.x;
            Xs[lk + 1][m] = x.y;
            Xs[lk + 2][m] = x.z;
            Xs[lk + 3][m] = x.w;
        }
        __syncthreads();
        // ---- compute chunk
        for (int lk = 0; lk < KC; ++lk) {
            const float4 w0 = *(const float4*)(Ws + lk * 512 + tj * 4);
            const float4 w1 = *(const float4*)(Ws + lk * 512 + (tj + 64) * 4);
            const float4 x0 = *(const float4*)(&Xs[lk][tm * 8]);
            const float4 x1 = *(const float4*)(&Xs[lk][tm * 8 + 4]);
            const float xm[8] = {x0.x, x0.y, x0.z, x0.w, x1.x, x1.y, x1.z, x1.w};
            const float wj[2][4] = {{w0.x, w0.y, w0.z, w0.w}, {w1.x, w1.y, w1.z, w1.w}};
            #pragma unroll
            for (int mm = 0; mm < 8; ++mm)
                #pragma unroll
                for (int jj = 0; jj < 2; ++jj)
                    #pragma unroll
                    for (int g = 0; g < 4; ++g)
                        acc[mm][jj][g] = fmaf(xm[mm], wj[jj][g], acc[mm][jj][g]);
        }
    }

    // ---- finalize: bias + LSTM cell, write h/c
    #pragma unroll
    for (int jj = 0; jj < 2; ++jj) {
        const int j = tj + 64 * jj;
        const float bi = bih[j]       + bhh[j];
        const float bf = bih[256 + j] + bhh[256 + j];
        const float bg = bih[512 + j] + bhh[512 + j];
        const float bo = bih[768 + j] + bhh[768 + j];
        #pragma unroll
        for (int mm = 0; mm < 8; ++mm) {
            const int mG = m0 + tm * 8 + mm;
            if (mG < n_l) {
                const float gi = acc[mm][jj][0] + bi;
                const float gf = acc[mm][jj][1] + bf;
                const float gg = acc[mm][jj][2] + bg;
                const float go = acc[mm][jj][3] + bo;
                const float c0 = has_h ? c_in[(2 * mG) * 128 + j] : 0.0f;
                const float cn = sigf(gf) * c0 + sigf(gi) * tanhf(gg);
                const float hn = sigf(go) * tanhf(cn);
                h_out[mG * 128 + j] = hn;
                c_out[mG * 128 + j] = cn;
            }
        }
    }
}

__global__ __launch_bounds__(128) void head_kernel(
    const float* __restrict__ hroot,    // 128
    const float* __restrict__ W1,       // 128 x 128
    const float* __restrict__ b1,       // 128
    const float* __restrict__ W2,       // 32 x 128
    const float* __restrict__ b2,       // 32
    const float* __restrict__ vmask,    // 32
    float* __restrict__ out)            // 32
{
    __shared__ float hs[128];
    __shared__ float as[128];
    const int t = threadIdx.x;
    hs[t] = hroot[t];
    __syncthreads();
    float acc = b1[t];
    #pragma unroll 4
    for (int k = 0; k < 128; ++k) acc = fmaf(hs[k], W1[t * 128 + k], acc);
    as[t] = fmaxf(acc, 0.0f);
    __syncthreads();
    if (t < 32) {
        float l = b2[t];
        #pragma unroll 4
        for (int k = 0; k < 128; ++k) l = fmaf(as[k], W2[t * 128 + k], l);
        l = (l + logf(vmask[t])) * (1.0f / 3.0f);
        float mx = l;
        #pragma unroll
        for (int o = 16; o >= 1; o >>= 1) mx = fmaxf(mx, __shfl_xor(mx, o, 32));
        const float e = expf(l - mx);
        float s = e;
        #pragma unroll
        for (int o = 16; o >= 1; o >>= 1) s += __shfl_xor(s, o, 32);
        out[t] = e / s;
    }
}

extern "C" void kernel_launch(void* const* d_in, const int* in_sizes, int n_in,
                              void* d_out, int out_size, void* d_ws, size_t ws_size,
                              hipStream_t stream)
{
    const int*   node_types = (const int*)  d_in[0];
    const float* node_args  = (const float*)d_in[1];
    const float* vmask      = (const float*)d_in[2];
    const float* emb        = (const float*)d_in[3];
    const float* Wih        = (const float*)d_in[4];
    const float* Whh        = (const float*)d_in[5];
    const float* bih        = (const float*)d_in[6];
    const float* bhh        = (const float*)d_in[7];
    const float* W1         = (const float*)d_in[8];
    const float* b1         = (const float*)d_in[9];
    const float* W2         = (const float*)d_in[10];
    const float* b2         = (const float*)d_in[11];

    // ping-pong h/c buffers in workspace:
    // A holds outputs of levels 15,13,11,... (max 32768 rows)
    // B holds outputs of levels 14,12,10,... (max 16384 rows)
    float* hA = (float*)d_ws;
    float* cA = hA + (size_t)32768 * 128;
    float* hB = cA + (size_t)32768 * 128;
    float* cB = hB + (size_t)16384 * 128;

    const float* h_prev = nullptr;
    const float* c_prev = nullptr;
    for (int lvl = DEPTH - 1; lvl >= 0; --lvl) {
        const int n_l = 1 << lvl;
        const int start = n_l - 1;
        const bool toA = (((DEPTH - 1 - lvl) & 1) == 0);
        float* ho = toA ? hA : hB;
        float* co = toA ? cA : cB;
        const int grid = (n_l + MT - 1) / MT;
        tree_lstm_level<<<grid, 256, 0, stream>>>(
            node_types, node_args, emb, Wih, Whh, bih, bhh,
            h_prev, c_prev, ho, co, start, n_l, (lvl == DEPTH - 1) ? 0 : 1);
        h_prev = ho; c_prev = co;
    }
    head_kernel<<<1, 128, 0, stream>>>(h_prev, W1, b1, W2, b2, vmask, (float*)d_out);
}

// Round 2
// 221.547 us; speedup vs baseline: 10.4078x; 10.4078x over previous
//
#include <hip/hip_runtime.h>
#include <hip/hip_bf16.h>

#define DEPTH 16

typedef __attribute__((ext_vector_type(8))) short s8v;   // 8 x bf16 (4 VGPR)
typedef __attribute__((ext_vector_type(4))) float f32x4; // MFMA acc

__device__ __forceinline__ float sigf(float x) { return 1.0f / (1.0f + expf(-x)); }
__device__ __forceinline__ ushort f2bf(float f) {
    union { __hip_bfloat16 b; ushort u; } v; v.b = __float2bfloat16(f); return v.u;
}
__device__ __forceinline__ float bf2f(ushort u) {
    union { float f; unsigned int i; } v; v.i = ((unsigned int)u) << 16; return v.f;
}

// ---------------- prepass 1: pack effective weights + fused bias ----------------
// Effective gate columns: (g, j) -> original row g*256 + j, g in [0,4), j in [0,128).
// Bpack element layout: (((bn*12 + kk)*4 + seg)*128 + nl)*8 + t
//   bn in [0,4): block n-tile (j range [32bn, 32bn+32))
//   kk in [0,12): K step of 32;  seg in [0,4): lane k-segment of 8;  t: k within run
//   nl in [0,128): local col = g*32 + jj
__global__ __launch_bounds__(256) void pack_weights(
    const float* __restrict__ Wih, const float* __restrict__ Whh,
    const float* __restrict__ bih, const float* __restrict__ bhh,
    ushort* __restrict__ Bpack, float* __restrict__ bsum)
{
    const int gid = blockIdx.x * 256 + threadIdx.x;
    if (gid < 24576) {
        const int nl  = gid & 127;
        const int seg = (gid >> 7) & 3;
        const int rest = gid >> 9;
        const int kk = rest % 12;
        const int bn = rest / 12;
        const int g  = nl >> 5;
        const int j  = bn * 32 + (nl & 31);
        const int row = g * 256 + j;
        const int k = kk * 32 + seg * 8;
        const float* src = (k < 128) ? (Wih + (size_t)row * 128 + k)
                                     : (Whh + (size_t)row * 256 + (k - 128));
        float4 w0 = *(const float4*)(src);
        float4 w1 = *(const float4*)(src + 4);
        ushort o[8] = { f2bf(w0.x), f2bf(w0.y), f2bf(w0.z), f2bf(w0.w),
                        f2bf(w1.x), f2bf(w1.y), f2bf(w1.z), f2bf(w1.w) };
        *(s8v*)(Bpack + (size_t)gid * 8) = *(const s8v*)o;
    }
    if (gid < 512) {  // bsum[g*128 + j]
        const int row = (gid >> 7) * 256 + (gid & 127);
        bsum[gid] = bih[row] + bhh[row];
    }
}

// ---------------- prepass 2: bf16 embedding gather for all nodes ----------------
__global__ __launch_bounds__(256) void build_xall(
    const int* __restrict__ node_types, const float* __restrict__ node_args,
    const float* __restrict__ emb, ushort* __restrict__ xall)
{
    const int gid = blockIdx.x * 256 + threadIdx.x;
    const int node = gid >> 4;
    const int run  = gid & 15;
    if (node >= 65535) return;
    const int ty = node_types[node];
    const float* src = emb + (size_t)ty * 128 + run * 8;
    float4 w0 = *(const float4*)(src);
    float4 w1 = *(const float4*)(src + 4);
    if (run == 15 && (ty == 1 || ty == 2)) w1.w = node_args[node];
    ushort o[8] = { f2bf(w0.x), f2bf(w0.y), f2bf(w0.z), f2bf(w0.w),
                    f2bf(w1.x), f2bf(w1.y), f2bf(w1.z), f2bf(w1.w) };
    *(s8v*)(xall + (size_t)node * 128 + run * 8) = *(const s8v*)o;
}

// ---------------- per-level GEMM + LSTM cell ----------------
// A[m][k]: k<128 -> xall[start+m]; k in [128,384) -> h_in[2m or 2m+1].
// B: Bpack (effective W^T, fragment-packed).  Gates -> LDS -> cell -> h(bf16), c(fp32 compact even rows).
__global__ __launch_bounds__(256) void level_gemm(
    const ushort* __restrict__ xall, const ushort* __restrict__ Bpack,
    const float* __restrict__ bsum,
    const ushort* __restrict__ h_in, const float* __restrict__ c_in,
    ushort* __restrict__ h_out, float* __restrict__ c_out,
    int start, int n_l, int nk)
{
    __shared__ float Gs[64][128];

    const int tid  = threadIdx.x;
    const int lane = tid & 63;
    const int wave = tid >> 6;
    const int wm   = wave >> 1;   // 0..1
    const int wn   = wave & 1;    // 0..1
    const int bn   = blockIdx.y;  // 0..3 (j range)
    const int m0   = blockIdx.x * 64;

    const int lc   = lane & 15;   // frag col / row-in-tile
    const int seg  = lane >> 4;   // k segment
    const int koff = seg * 8;

    // A pointers (clamped rows for partial tiles)
    const ushort* pax[2];
    const ushort* pah[2][2];
    #pragma unroll
    for (int mi = 0; mi < 2; ++mi) {
        int m = m0 + wm * 32 + mi * 16 + lc;
        int mc = m < n_l ? m : n_l - 1;
        pax[mi]    = xall + (size_t)(start + mc) * 128 + koff;
        pah[mi][0] = h_in + (size_t)(2 * mc) * 128 + koff;
        pah[mi][1] = h_in + (size_t)(2 * mc + 1) * 128 + koff;
    }
    // B pointer: (((bn*12+kk)*4+seg)*128 + wn*64 + f*16 + lc) * 8
    const ushort* pb = Bpack + (size_t)bn * 12 * 4096 + (size_t)seg * 1024
                             + (size_t)(wn * 64 + lc) * 8;

    f32x4 acc[2][4];
    #pragma unroll
    for (int mi = 0; mi < 2; ++mi)
        #pragma unroll
        for (int f = 0; f < 4; ++f) acc[mi][f] = (f32x4){0.f, 0.f, 0.f, 0.f};

    // K part 1: embedding (k = 0..127)
    #pragma unroll
    for (int kk = 0; kk < 4; ++kk) {
        s8v a0 = *(const s8v*)(pax[0] + kk * 32);
        s8v a1 = *(const s8v*)(pax[1] + kk * 32);
        #pragma unroll
        for (int f = 0; f < 4; ++f) {
            s8v b = *(const s8v*)(pb + (size_t)kk * 4096 + f * 128);
            acc[0][f] = __builtin_amdgcn_mfma_f32_16x16x32_bf16(a0, b, acc[0][f], 0, 0, 0);
            acc[1][f] = __builtin_amdgcn_mfma_f32_16x16x32_bf16(a1, b, acc[1][f], 0, 0, 0);
        }
    }
    // K part 2: children h (k = 128..383)
    if (nk == 12) {
        #pragma unroll
        for (int kk = 0; kk < 8; ++kk) {
            const int hi  = kk >> 2;
            const int off = (kk & 3) * 32;
            s8v a0 = *(const s8v*)(pah[0][hi] + off);
            s8v a1 = *(const s8v*)(pah[1][hi] + off);
            #pragma unroll
            for (int f = 0; f < 4; ++f) {
                s8v b = *(const s8v*)(pb + (size_t)(kk + 4) * 4096 + f * 128);
                acc[0][f] = __builtin_amdgcn_mfma_f32_16x16x32_bf16(a0, b, acc[0][f], 0, 0, 0);
                acc[1][f] = __builtin_amdgcn_mfma_f32_16x16x32_bf16(a1, b, acc[1][f], 0, 0, 0);
            }
        }
    }

    // dump gates to LDS: D row = (lane>>4)*4 + r, col = lane&15
    #pragma unroll
    for (int mi = 0; mi < 2; ++mi)
        #pragma unroll
        for (int f = 0; f < 4; ++f)
            #pragma unroll
            for (int r = 0; r < 4; ++r)
                Gs[wm * 32 + mi * 16 + seg * 4 + r][wn * 64 + f * 16 + lc] = acc[mi][f][r];
    __syncthreads();

    // LSTM cell epilogue: p = (m_local, jj)
    const bool has_h = (nk == 12);
    #pragma unroll
    for (int q = 0; q < 8; ++q) {
        const int p = tid + 256 * q;
        const int m_local = p >> 5;
        const int jj = p & 31;
        const int m = m0 + m_local;
        if (m < n_l) {
            const int j = bn * 32 + jj;
            const float gi = Gs[m_local][jj]      + bsum[j];
            const float gf = Gs[m_local][32 + jj] + bsum[128 + j];
            const float gg = Gs[m_local][64 + jj] + bsum[256 + j];
            const float go = Gs[m_local][96 + jj] + bsum[384 + j];
            const float c0 = has_h ? c_in[(size_t)m * 128 + j] : 0.0f;
            const float cn = sigf(gf) * c0 + sigf(gi) * tanhf(gg);
            const float hn = sigf(go) * tanhf(cn);
            h_out[(size_t)m * 128 + j] = f2bf(hn);
            if (!(m & 1)) c_out[(size_t)(m >> 1) * 128 + j] = cn;
        }
    }
}

// ---------------- head: relu(h W1^T + b1) W2^T + b2 + log(mask) -> softmax/T ----------------
__global__ __launch_bounds__(128) void head_kernel(
    const ushort* __restrict__ hroot,
    const float* __restrict__ W1, const float* __restrict__ b1,
    const float* __restrict__ W2, const float* __restrict__ b2,
    const float* __restrict__ vmask, float* __restrict__ out)
{
    __shared__ float hs[128];
    __shared__ float as[128];
    const int t = threadIdx.x;
    hs[t] = bf2f(hroot[t]);
    __syncthreads();
    float acc = b1[t];
    #pragma unroll 4
    for (int k = 0; k < 128; ++k) acc = fmaf(hs[k], W1[t * 128 + k], acc);
    as[t] = fmaxf(acc, 0.0f);
    __syncthreads();
    if (t < 32) {
        float l = b2[t];
        #pragma unroll 4
        for (int k = 0; k < 128; ++k) l = fmaf(as[k], W2[t * 128 + k], l);
        l = (l + logf(vmask[t])) * (1.0f / 3.0f);
        float mx = l;
        #pragma unroll
        for (int o = 16; o >= 1; o >>= 1) mx = fmaxf(mx, __shfl_xor(mx, o, 32));
        const float e = expf(l - mx);
        float s = e;
        #pragma unroll
        for (int o = 16; o >= 1; o >>= 1) s += __shfl_xor(s, o, 32);
        out[t] = e / s;
    }
}

extern "C" void kernel_launch(void* const* d_in, const int* in_sizes, int n_in,
                              void* d_out, int out_size, void* d_ws, size_t ws_size,
                              hipStream_t stream)
{
    const int*   node_types = (const int*)  d_in[0];
    const float* node_args  = (const float*)d_in[1];
    const float* vmask      = (const float*)d_in[2];
    const float* emb        = (const float*)d_in[3];
    const float* Wih        = (const float*)d_in[4];
    const float* Whh        = (const float*)d_in[5];
    const float* bih        = (const float*)d_in[6];
    const float* bhh        = (const float*)d_in[7];
    const float* W1         = (const float*)d_in[8];
    const float* b1         = (const float*)d_in[9];
    const float* W2         = (const float*)d_in[10];
    const float* b2         = (const float*)d_in[11];

    char* w = (char*)d_ws;
    ushort* xall  = (ushort*)(w);                 // 65536*128*2      = 16,777,216
    ushort* Bpack = (ushort*)(w + 16777216);      // 24576*8*2        =    393,216
    float*  bsum  = (float*) (w + 17170432);      // 512*4            =      2,048
    ushort* hA    = (ushort*)(w + 17172480);      // 32768*128*2      =  8,388,608
    ushort* hB    = (ushort*)(w + 25561088);      // 16384*128*2      =  4,194,304
    float*  cA    = (float*) (w + 29755392);      // 16384*128*4      =  8,388,608
    float*  cB    = (float*) (w + 38144000);      // 8192*128*4       =  4,194,304

    pack_weights<<<96, 256, 0, stream>>>(Wih, Whh, bih, bhh, Bpack, bsum);
    build_xall<<<4096, 256, 0, stream>>>(node_types, node_args, emb, xall);

    const ushort* h_prev = hA;   // dummy (unread at leaf level)
    const float*  c_prev = cA;
    for (int lvl = DEPTH - 1; lvl >= 0; --lvl) {
        const int n_l = 1 << lvl;
        const int start = n_l - 1;
        const bool toA = (((DEPTH - 1 - lvl) & 1) == 0);
        ushort* ho = toA ? hA : hB;
        float*  co = toA ? cA : cB;
        const int nk = (lvl == DEPTH - 1) ? 4 : 12;
        dim3 grid((n_l + 63) / 64, 4);
        level_gemm<<<grid, 256, 0, stream>>>(
            xall, Bpack, bsum, h_prev, c_prev, ho, co, start, n_l, nk);
        h_prev = ho; c_prev = co;
    }
    head_kernel<<<1, 128, 0, stream>>>(h_prev, W1, b1, W2, b2, vmask, (float*)d_out);
}